// Round 6
// baseline (833.904 us; speedup 1.0000x reference)
//
#include <hip/hip_runtime.h>
#include <hip/hip_bf16.h>

typedef __bf16 bf16;
typedef __bf16 bf16x4 __attribute__((ext_vector_type(4)));
typedef __bf16 bf16x8 __attribute__((ext_vector_type(8)));
typedef float  f32x4 __attribute__((ext_vector_type(4)));

#define MFMA16(a, b, c) __builtin_amdgcn_mfma_f32_16x16x32_bf16((a), (b), (c), 0, 0, 0)

// async 16B/lane global->LDS (m97). LDS dst = uniform base + lane*16.
#define GLOBAL_LOAD_LDS16(gp, lp)                                                     \
    __builtin_amdgcn_global_load_lds(                                                 \
        (const __attribute__((address_space(1))) void*)(gp),                          \
        (__attribute__((address_space(3))) void*)(lp), 16, 0, 0)

// ---------------------------------------------------------------------------
// fp32 -> bf16, two sources into one contiguous dst (8 elems/thread)
__global__ __launch_bounds__(256)
void cvt2(const float* __restrict__ s1, const float* __restrict__ s2,
          bf16* __restrict__ dst, int n1, int ntot)
{
    int i = blockIdx.x * 256 + threadIdx.x;
    if (i >= ntot) return;
    const float* s = (i < n1) ? s1 + (size_t)i * 8 : s2 + (size_t)(i - n1) * 8;
    f32x4 a = *reinterpret_cast<const f32x4*>(s);
    f32x4 b = *reinterpret_cast<const f32x4*>(s + 4);
    bf16x8 r;
#pragma unroll
    for (int u = 0; u < 4; u++) { r[u] = (bf16)a[u]; r[u + 4] = (bf16)b[u]; }
    *reinterpret_cast<bf16x8*>(dst + (size_t)i * 8) = r;
}

// ---------------------------------------------------------------------------
// Merged QKV projection: C = X[4096,1024] * Wqkv[3072,1024]^T, one dispatch.
// 128x128 tiles, BK=32, global_load_lds, swapped MFMA (B-first):
//   lane: m = 16-block + ln16 (fixed), n = 16-block + quad*4 + r (consecutive).
// Epilogue: n0 < 2048 -> qk[m][n] packed 8B; n0 >= 2048 -> vt[n-2048][m]
// transposed scalar stores (16 lanes = 32B segments).
__global__ __launch_bounds__(256)
void gemm_qkv(const bf16* __restrict__ A, const bf16* __restrict__ B,
              bf16* __restrict__ qk, bf16* __restrict__ vt)
{
    constexpr int K = 1024, LD = 1024, M = 4096;
    __shared__ __align__(16) bf16 As[128 * 32];
    __shared__ __align__(16) bf16 Bs[128 * 32];

    const int t = threadIdx.x;
    const int w = t >> 6, lane = t & 63, quad = lane >> 4, ln16 = lane & 15;
    const int m0 = blockIdx.y * 128, n0 = blockIdx.x * 128;
    const int wr = (w >> 1) * 64, wc = (w & 1) * 64;
    const int srow = lane >> 2;
    const int scol = (lane & 3) * 8;

    f32x4 acc[4][4] = {};

    for (int k0 = 0; k0 < K; k0 += 32) {
        __syncthreads();
#pragma unroll
        for (int p = 0; p < 2; p++) {
            const int op = w * 2 + p;
            const int row = op * 16 + srow;
            GLOBAL_LOAD_LDS16(A + (size_t)(m0 + row) * LD + k0 + scol, &As[op * 512]);
            GLOBAL_LOAD_LDS16(B + (size_t)(n0 + row) * LD + k0 + scol, &Bs[op * 512]);
        }
        __syncthreads();

        bf16x8 af[4];
#pragma unroll
        for (int mb = 0; mb < 4; mb++)
            af[mb] = *reinterpret_cast<const bf16x8*>(&As[(wr + mb * 16 + ln16) * 32 + quad * 8]);
#pragma unroll
        for (int nb = 0; nb < 4; nb++) {
            bf16x8 bv = *reinterpret_cast<const bf16x8*>(&Bs[(wc + nb * 16 + ln16) * 32 + quad * 8]);
#pragma unroll
            for (int mb = 0; mb < 4; mb++)
                acc[mb][nb] = MFMA16(bv, af[mb], acc[mb][nb]);
        }
    }

    if (n0 < 2048) {
#pragma unroll
        for (int mb = 0; mb < 4; mb++)
#pragma unroll
            for (int nb = 0; nb < 4; nb++) {
                size_t idx = (size_t)(m0 + wr + mb * 16 + ln16) * 2048
                           + (n0 + wc + nb * 16 + quad * 4);
                bf16x4 v;
#pragma unroll
                for (int r = 0; r < 4; r++) v[r] = (bf16)acc[mb][nb][r];
                *reinterpret_cast<bf16x4*>(&qk[idx]) = v;
            }
    } else {
#pragma unroll
        for (int mb = 0; mb < 4; mb++)
#pragma unroll
            for (int nb = 0; nb < 4; nb++)
#pragma unroll
                for (int r = 0; r < 4; r++) {
                    const int e = n0 - 2048 + wc + nb * 16 + quad * 4 + r;
                    vt[(size_t)e * M + m0 + wr + mb * 16 + ln16] = (bf16)acc[mb][nb][r];
                }
    }
}

// ---------------------------------------------------------------------------
// Out projection: C[m][n] = A[M,K] * B[N,K]^T, fp32 packed 16B stores.
__global__ __launch_bounds__(256)
void gemm_out(const bf16* __restrict__ A, const bf16* __restrict__ B,
              float* __restrict__ C)
{
    constexpr int K = 1024, LD = 1024;
    __shared__ __align__(16) bf16 As[128 * 32];
    __shared__ __align__(16) bf16 Bs[128 * 32];

    const int t = threadIdx.x;
    const int w = t >> 6, lane = t & 63, quad = lane >> 4, ln16 = lane & 15;
    const int m0 = blockIdx.y * 128, n0 = blockIdx.x * 128;
    const int wr = (w >> 1) * 64, wc = (w & 1) * 64;
    const int srow = lane >> 2;
    const int scol = (lane & 3) * 8;

    f32x4 acc[4][4] = {};

    for (int k0 = 0; k0 < K; k0 += 32) {
        __syncthreads();
#pragma unroll
        for (int p = 0; p < 2; p++) {
            const int op = w * 2 + p;
            const int row = op * 16 + srow;
            GLOBAL_LOAD_LDS16(A + (size_t)(m0 + row) * LD + k0 + scol, &As[op * 512]);
            GLOBAL_LOAD_LDS16(B + (size_t)(n0 + row) * LD + k0 + scol, &Bs[op * 512]);
        }
        __syncthreads();

        bf16x8 af[4];
#pragma unroll
        for (int mb = 0; mb < 4; mb++)
            af[mb] = *reinterpret_cast<const bf16x8*>(&As[(wr + mb * 16 + ln16) * 32 + quad * 8]);
#pragma unroll
        for (int nb = 0; nb < 4; nb++) {
            bf16x8 bv = *reinterpret_cast<const bf16x8*>(&Bs[(wc + nb * 16 + ln16) * 32 + quad * 8]);
#pragma unroll
            for (int mb = 0; mb < 4; mb++)
                acc[mb][nb] = MFMA16(bv, af[mb], acc[mb][nb]);
        }
    }

#pragma unroll
    for (int mb = 0; mb < 4; mb++)
#pragma unroll
        for (int nb = 0; nb < 4; nb++) {
            size_t idx = (size_t)(m0 + wr + mb * 16 + ln16) * LD
                       + (n0 + wc + nb * 16 + quad * 4);
            *reinterpret_cast<f32x4*>(&C[idx]) = acc[mb][nb];
        }
}

// ---------------------------------------------------------------------------
// Fused causal flash attention v5.
//  - swapped S-MFMA: lane holds S^T[key=quad*4+r][q=ln16] -> Ps writes packed 8B.
//  - prefetch depth 2 (register pipeline of K/V tiles).
//  - uniform-work chunks: j = bx&31, (b,h) = bx>>5 (head-shared L2, no work skew
//    across chunks).
//  - ones rows 64..79 of VTs: PV MFMA nb=4 yields row-sum l per-lane for free.
__global__ __launch_bounds__(256)
void attn_flash5(const bf16* __restrict__ qk, const bf16* __restrict__ vt,
                 bf16* __restrict__ z)
{
    constexpr int Tn = 2048, Dm = 1024, QLD = 2048, VLD = 4096;
    constexpr int KP = 72;
    __shared__ __align__(16) bf16 Ks[64 * KP];
    __shared__ __align__(16) bf16 VTs[80 * KP];  // rows 64..79 = ones
    __shared__ __align__(16) bf16 Ps[64 * KP];

    const int t = threadIdx.x;
    const int w = t >> 6, lane = t & 63, quad = lane >> 4, ln16 = lane & 15;
    const int g = blockIdx.x >> 5;
    const int j = blockIdx.x & 31;
    const int b = g >> 4, h = g & 15;
    const int q0 = j * 64;

    const bf16* Qb = qk + (size_t)b * Tn * QLD + h * 64;
    const bf16* Kb = Qb + 1024;
    const bf16* Vb = vt + (size_t)(h * 64) * VLD + b * Tn;

    // ones rows for the l-column trick
    for (int i = t; i < 16 * KP; i += 256) VTs[64 * KP + i] = (bf16)1.0f;

    // Q frags in registers, pre-scaled by scale*log2(e). Register layout is a
    // valid B-operand (n=ln16=q, k=quad*8+u) for the swapped S-MFMA.
    constexpr float C2 = 0.125f * 1.44269504089f;
    bf16x8 qf[2];
#pragma unroll
    for (int kki = 0; kki < 2; kki++) {
        bf16x8 q = *reinterpret_cast<const bf16x8*>(
            Qb + (size_t)(q0 + w * 16 + ln16) * QLD + kki * 32 + quad * 8);
#pragma unroll
        for (int u = 0; u < 8; u++) qf[kki][u] = (bf16)((float)q[u] * C2);
    }

    const int sr = t >> 3;          // staging row 0..31 (+32 second pass)
    const int sseg = (t & 7) * 8;

    // register pipeline: tiles kt and kt+1
    bf16x8 kr[2][2], vr[2][2];
#pragma unroll
    for (int p = 0; p < 2; p++) {
        kr[0][p] = *reinterpret_cast<const bf16x8*>(Kb + (size_t)(sr + p * 32) * QLD + sseg);
        vr[0][p] = *reinterpret_cast<const bf16x8*>(Vb + (size_t)(sr + p * 32) * VLD + sseg);
    }
    if (j >= 1) {
#pragma unroll
        for (int p = 0; p < 2; p++) {
            kr[1][p] = *reinterpret_cast<const bf16x8*>(Kb + (size_t)(64 + sr + p * 32) * QLD + sseg);
            vr[1][p] = *reinterpret_cast<const bf16x8*>(Vb + (size_t)(sr + p * 32) * VLD + 64 + sseg);
        }
    }

    f32x4 accO[5] = {};  // [0..3] = O^T (d on quad*4+r, q on ln16), [4] = l
    const int qloc = w * 16 + ln16;  // lane's local q row

    for (int kt = 0; kt <= j; kt++) {
        const int cur = kt & 1;
        __syncthreads();  // all waves done reading Ks/VTs/Ps of prev iter
#pragma unroll
        for (int p = 0; p < 2; p++) {
            *reinterpret_cast<bf16x8*>(&Ks[(sr + p * 32) * KP + sseg]) = kr[cur][p];
            *reinterpret_cast<bf16x8*>(&VTs[(sr + p * 32) * KP + sseg]) = vr[cur][p];
        }
        __syncthreads();

        if (kt + 2 <= j) {  // refill the just-consumed slot, 2 tiles ahead
            const int k2 = (kt + 2) * 64;
#pragma unroll
            for (int p = 0; p < 2; p++) {
                kr[cur][p] = *reinterpret_cast<const bf16x8*>(
                    Kb + (size_t)(k2 + sr + p * 32) * QLD + sseg);
                vr[cur][p] = *reinterpret_cast<const bf16x8*>(
                    Vb + (size_t)(sr + p * 32) * VLD + k2 + sseg);
            }
        }

        // ---- S^T = K (C2*Q)^T : lane holds key=nb*16+quad*4+r, q=ln16 ----
        f32x4 aS[4] = {};
#pragma unroll
        for (int kki = 0; kki < 2; kki++)
#pragma unroll
            for (int nb = 0; nb < 4; nb++) {
                bf16x8 kb = *reinterpret_cast<const bf16x8*>(
                    &Ks[(nb * 16 + ln16) * KP + kki * 32 + quad * 8]);
                aS[nb] = MFMA16(kb, qf[kki], aS[nb]);
            }

        // ---- p = 2^s; mask only diagonal tile; packed 8B Ps writes ----
        if (kt == j) {
#pragma unroll
            for (int nb = 0; nb < 4; nb++) {
                bf16x4 pv;
#pragma unroll
                for (int r = 0; r < 4; r++) {
                    float p = __builtin_amdgcn_exp2f(aS[nb][r]);
                    if ((nb * 16 + quad * 4 + r) > qloc) p = 0.f;
                    pv[r] = (bf16)p;
                }
                *reinterpret_cast<bf16x4*>(&Ps[qloc * KP + nb * 16 + quad * 4]) = pv;
            }
        } else {
#pragma unroll
            for (int nb = 0; nb < 4; nb++) {
                bf16x4 pv;
#pragma unroll
                for (int r = 0; r < 4; r++)
                    pv[r] = (bf16)__builtin_amdgcn_exp2f(aS[nb][r]);
                *reinterpret_cast<bf16x4*>(&Ps[qloc * KP + nb * 16 + quad * 4]) = pv;
            }
        }
        // wave-private Ps round-trip: wait own DS writes only
        asm volatile("s_waitcnt lgkmcnt(0)" ::: "memory");

        // ---- O^T += V^T P^T ; nb=4 (ones rows) accumulates l ----
#pragma unroll
        for (int kki = 0; kki < 2; kki++) {
            bf16x8 pa = *reinterpret_cast<const bf16x8*>(
                &Ps[qloc * KP + kki * 32 + quad * 8]);
#pragma unroll
            for (int nb = 0; nb < 5; nb++) {
                bf16x8 vb = *reinterpret_cast<const bf16x8*>(
                    &VTs[(nb * 16 + ln16) * KP + kki * 32 + quad * 8]);
                accO[nb] = MFMA16(vb, pa, accO[nb]);
            }
        }
    }

    // ---- epilogue: lane owns q-row = qloc; l = accO[4][0]; packed 8B ----
    const float linv = 1.0f / accO[4][0];
    const size_t zr = ((size_t)b * Tn + q0 + qloc) * Dm + h * 64;
#pragma unroll
    for (int nb = 0; nb < 4; nb++) {
        bf16x4 v;
#pragma unroll
        for (int r = 0; r < 4; r++) v[r] = (bf16)(accO[nb][r] * linv);
        *reinterpret_cast<bf16x4*>(z + zr + nb * 16 + quad * 4) = v;
    }
}

// ---------------------------------------------------------------------------
extern "C" void kernel_launch(void* const* d_in, const int* in_sizes, int n_in,
                              void* d_out, int out_size, void* d_ws, size_t ws_size,
                              hipStream_t stream)
{
    constexpr int B = 2, T = 2048, D = 1024;
    constexpr int M = B * T;  // 4096

    const float* X    = (const float*)d_in[0];
    const float* Wqkv = (const float*)d_in[1];
    const float* Wout = (const float*)d_in[2];
    float* out = (float*)d_out;

    // ws: qk [M][2048] 16 MiB | vt [1024][M] 8 MiB | z [M][1024] 8 MiB
    bf16* qk  = (bf16*)d_ws;
    bf16* vt  = qk + (size_t)M * 2048;
    bf16* zbf = vt + (size_t)1024 * M;
    // d_out as scratch until gemm_out writes it
    bf16* Xbf    = (bf16*)d_out;
    bf16* Wqkvbf = Xbf + (size_t)M * D;
    bf16* Woutbf = qk;  // reuse qk region after attention consumed it

    dim3 blk(256);
    const int n1 = M * D / 8, n2 = 3 * D * D / 8;
    cvt2<<<(n1 + n2 + 255) / 256, blk, 0, stream>>>(X, Wqkv, Xbf, n1, n1 + n2);

    // qk + vt in ONE dispatch (768 blocks)
    gemm_qkv<<<dim3(24, 32), blk, 0, stream>>>(Xbf, Wqkvbf, qk, vt);

    attn_flash5<<<dim3(1024), blk, 0, stream>>>(qk, vt, zbf);

    const int n3 = D * D / 8;
    cvt2<<<(n3 + 255) / 256, blk, 0, stream>>>(Wout, Wout, Woutbf, n3, n3);

    gemm_out<<<dim3(8, 32), blk, 0, stream>>>(zbf, Woutbf, out);
}

// Round 7
// 182.048 us; speedup vs baseline: 4.5807x; 4.5807x over previous
//
#include <hip/hip_runtime.h>
#include <hip/hip_bf16.h>

typedef __bf16 bf16;
typedef __bf16 bf16x4 __attribute__((ext_vector_type(4)));
typedef __bf16 bf16x8 __attribute__((ext_vector_type(8)));
typedef float  f32x4 __attribute__((ext_vector_type(4)));

#define MFMA16(a, b, c) __builtin_amdgcn_mfma_f32_16x16x32_bf16((a), (b), (c), 0, 0, 0)

// async 16B/lane global->LDS (m97). LDS dst = uniform base + lane*16.
#define GLOBAL_LOAD_LDS16(gp, lp)                                                     \
    __builtin_amdgcn_global_load_lds(                                                 \
        (const __attribute__((address_space(1))) void*)(gp),                          \
        (__attribute__((address_space(3))) void*)(lp), 16, 0, 0)

// ---------------------------------------------------------------------------
// fp32 -> bf16, two sources into one contiguous dst (8 elems/thread)
__global__ __launch_bounds__(256)
void cvt2(const float* __restrict__ s1, const float* __restrict__ s2,
          bf16* __restrict__ dst, int n1, int ntot)
{
    int i = blockIdx.x * 256 + threadIdx.x;
    if (i >= ntot) return;
    const float* s = (i < n1) ? s1 + (size_t)i * 8 : s2 + (size_t)(i - n1) * 8;
    f32x4 a = *reinterpret_cast<const f32x4*>(s);
    f32x4 b = *reinterpret_cast<const f32x4*>(s + 4);
    bf16x8 r;
#pragma unroll
    for (int u = 0; u < 4; u++) { r[u] = (bf16)a[u]; r[u + 4] = (bf16)b[u]; }
    *reinterpret_cast<bf16x8*>(dst + (size_t)i * 8) = r;
}

// ---------------------------------------------------------------------------
// Merged QKV projection (R6, kept: non-attn time 161->108 us).
__global__ __launch_bounds__(256)
void gemm_qkv(const bf16* __restrict__ A, const bf16* __restrict__ B,
              bf16* __restrict__ qk, bf16* __restrict__ vt)
{
    constexpr int K = 1024, LD = 1024, M = 4096;
    __shared__ __align__(16) bf16 As[128 * 32];
    __shared__ __align__(16) bf16 Bs[128 * 32];

    const int t = threadIdx.x;
    const int w = t >> 6, lane = t & 63, quad = lane >> 4, ln16 = lane & 15;
    const int m0 = blockIdx.y * 128, n0 = blockIdx.x * 128;
    const int wr = (w >> 1) * 64, wc = (w & 1) * 64;
    const int srow = lane >> 2;
    const int scol = (lane & 3) * 8;

    f32x4 acc[4][4] = {};

    for (int k0 = 0; k0 < K; k0 += 32) {
        __syncthreads();
#pragma unroll
        for (int p = 0; p < 2; p++) {
            const int op = w * 2 + p;
            const int row = op * 16 + srow;
            GLOBAL_LOAD_LDS16(A + (size_t)(m0 + row) * LD + k0 + scol, &As[op * 512]);
            GLOBAL_LOAD_LDS16(B + (size_t)(n0 + row) * LD + k0 + scol, &Bs[op * 512]);
        }
        __syncthreads();

        bf16x8 af[4];
#pragma unroll
        for (int mb = 0; mb < 4; mb++)
            af[mb] = *reinterpret_cast<const bf16x8*>(&As[(wr + mb * 16 + ln16) * 32 + quad * 8]);
#pragma unroll
        for (int nb = 0; nb < 4; nb++) {
            bf16x8 bv = *reinterpret_cast<const bf16x8*>(&Bs[(wc + nb * 16 + ln16) * 32 + quad * 8]);
#pragma unroll
            for (int mb = 0; mb < 4; mb++)
                acc[mb][nb] = MFMA16(bv, af[mb], acc[mb][nb]);
        }
    }

    if (n0 < 2048) {
#pragma unroll
        for (int mb = 0; mb < 4; mb++)
#pragma unroll
            for (int nb = 0; nb < 4; nb++) {
                size_t idx = (size_t)(m0 + wr + mb * 16 + ln16) * 2048
                           + (n0 + wc + nb * 16 + quad * 4);
                bf16x4 v;
#pragma unroll
                for (int r = 0; r < 4; r++) v[r] = (bf16)acc[mb][nb][r];
                *reinterpret_cast<bf16x4*>(&qk[idx]) = v;
            }
    } else {
#pragma unroll
        for (int mb = 0; mb < 4; mb++)
#pragma unroll
            for (int nb = 0; nb < 4; nb++)
#pragma unroll
                for (int r = 0; r < 4; r++) {
                    const int e = n0 - 2048 + wc + nb * 16 + quad * 4 + r;
                    vt[(size_t)e * M + m0 + wr + mb * 16 + ln16] = (bf16)acc[mb][nb][r];
                }
    }
}

// ---------------------------------------------------------------------------
// Out projection: C[m][n] = A[M,K] * B[N,K]^T, fp32 packed 16B stores.
__global__ __launch_bounds__(256)
void gemm_out(const bf16* __restrict__ A, const bf16* __restrict__ B,
              float* __restrict__ C)
{
    constexpr int K = 1024, LD = 1024;
    __shared__ __align__(16) bf16 As[128 * 32];
    __shared__ __align__(16) bf16 Bs[128 * 32];

    const int t = threadIdx.x;
    const int w = t >> 6, lane = t & 63, quad = lane >> 4, ln16 = lane & 15;
    const int m0 = blockIdx.y * 128, n0 = blockIdx.x * 128;
    const int wr = (w >> 1) * 64, wc = (w & 1) * 64;
    const int srow = lane >> 2;
    const int scol = (lane & 3) * 8;

    f32x4 acc[4][4] = {};

    for (int k0 = 0; k0 < K; k0 += 32) {
        __syncthreads();
#pragma unroll
        for (int p = 0; p < 2; p++) {
            const int op = w * 2 + p;
            const int row = op * 16 + srow;
            GLOBAL_LOAD_LDS16(A + (size_t)(m0 + row) * LD + k0 + scol, &As[op * 512]);
            GLOBAL_LOAD_LDS16(B + (size_t)(n0 + row) * LD + k0 + scol, &Bs[op * 512]);
        }
        __syncthreads();

        bf16x8 af[4];
#pragma unroll
        for (int mb = 0; mb < 4; mb++)
            af[mb] = *reinterpret_cast<const bf16x8*>(&As[(wr + mb * 16 + ln16) * 32 + quad * 8]);
#pragma unroll
        for (int nb = 0; nb < 4; nb++) {
            bf16x8 bv = *reinterpret_cast<const bf16x8*>(&Bs[(wc + nb * 16 + ln16) * 32 + quad * 8]);
#pragma unroll
            for (int mb = 0; mb < 4; mb++)
                acc[mb][nb] = MFMA16(bv, af[mb], acc[mb][nb]);
        }
    }

#pragma unroll
    for (int mb = 0; mb < 4; mb++)
#pragma unroll
        for (int nb = 0; nb < 4; nb++) {
            size_t idx = (size_t)(m0 + wr + mb * 16 + ln16) * LD
                       + (n0 + wc + nb * 16 + quad * 4);
            *reinterpret_cast<f32x4*>(&C[idx]) = acc[mb][nb];
        }
}

// ---------------------------------------------------------------------------
// Fused causal flash attention v6 = v4 skeleton (static single-slot prefetch,
// 58.9 us proven) + v5's swapped-S/packed-Ps + register-constant ones operand
// + perfectly balanced j-mapping (each CU slot sums to 66 tile-iters).
// NO dynamic register-array indexing (R6 lesson: it spills -> 12x regression).
__global__ __launch_bounds__(256)
void attn_flash6(const bf16* __restrict__ qk, const bf16* __restrict__ vt,
                 bf16* __restrict__ z)
{
    constexpr int Tn = 2048, Dm = 1024, QLD = 2048, VLD = 4096;
    constexpr int KP = 72;
    __shared__ __align__(16) bf16 Ks[64 * KP];
    __shared__ __align__(16) bf16 VTs[64 * KP];
    __shared__ __align__(16) bf16 Ps[64 * KP];

    const int t = threadIdx.x;
    const int w = t >> 6, lane = t & 63, quad = lane >> 4, ln16 = lane & 15;
    // balanced mapping: blocks bx, bx+256, bx+512, bx+768 (same CU slot) get
    // j = q0, 15-q0, 16+q0, 31-q0  -> constant 66 iters per CU slot.
    const int q = blockIdx.x >> 5, g = blockIdx.x & 31;
    const int s4 = q >> 3, q0i = q & 7;
    const int j = (s4 == 0) ? q0i : (s4 == 1) ? (15 - q0i)
                : (s4 == 2) ? (16 + q0i) : (31 - q0i);
    const int b = g >> 4, h = g & 15;
    const int q0 = j * 64;

    const bf16* Qb = qk + (size_t)b * Tn * QLD + h * 64;
    const bf16* Kb = Qb + 1024;
    const bf16* Vb = vt + (size_t)(h * 64) * VLD + b * Tn;

    // Q frags in registers, pre-scaled by scale*log2(e); valid B-operand for
    // the swapped S-MFMA (n=ln16=q-row, k=quad*8+u).
    constexpr float C2 = 0.125f * 1.44269504089f;
    bf16x8 qf[2];
#pragma unroll
    for (int kki = 0; kki < 2; kki++) {
        bf16x8 qv = *reinterpret_cast<const bf16x8*>(
            Qb + (size_t)(q0 + w * 16 + ln16) * QLD + kki * 32 + quad * 8);
#pragma unroll
        for (int u = 0; u < 8; u++) qf[kki][u] = (bf16)((float)qv[u] * C2);
    }

    // all-ones A-operand (replaces LDS ones rows): D = sum_k pa -> row-sum l
    bf16x8 vones;
#pragma unroll
    for (int u = 0; u < 8; u++) vones[u] = (bf16)1.0f;

    const int sr = t >> 3;          // staging row 0..31 (+32 second pass)
    const int sseg = (t & 7) * 8;

    // single-slot static prefetch registers (tile 0 preloaded)
    bf16x8 kreg[2], vreg[2];
#pragma unroll
    for (int p = 0; p < 2; p++) {
        kreg[p] = *reinterpret_cast<const bf16x8*>(Kb + (size_t)(sr + p * 32) * QLD + sseg);
        vreg[p] = *reinterpret_cast<const bf16x8*>(Vb + (size_t)(sr + p * 32) * VLD + sseg);
    }

    f32x4 accO[5] = {};  // [0..3] = O^T (d on quad*4+r, q on ln16), [4] = l
    const int qloc = w * 16 + ln16;  // lane's local q row

    for (int kt = 0; kt <= j; kt++) {
        __syncthreads();  // all waves done reading Ks/VTs of prev iter
#pragma unroll
        for (int p = 0; p < 2; p++) {
            *reinterpret_cast<bf16x8*>(&Ks[(sr + p * 32) * KP + sseg]) = kreg[p];
            *reinterpret_cast<bf16x8*>(&VTs[(sr + p * 32) * KP + sseg]) = vreg[p];
        }
        __syncthreads();

        if (kt < j) {  // prefetch next tile into the (static) registers
            const int k1 = (kt + 1) * 64;
#pragma unroll
            for (int p = 0; p < 2; p++) {
                kreg[p] = *reinterpret_cast<const bf16x8*>(
                    Kb + (size_t)(k1 + sr + p * 32) * QLD + sseg);
                vreg[p] = *reinterpret_cast<const bf16x8*>(
                    Vb + (size_t)(sr + p * 32) * VLD + k1 + sseg);
            }
        }

        // ---- S^T = K (C2*Q)^T : lane holds key=nb*16+quad*4+r, q=ln16 ----
        f32x4 aS[4] = {};
#pragma unroll
        for (int kki = 0; kki < 2; kki++)
#pragma unroll
            for (int nb = 0; nb < 4; nb++) {
                bf16x8 kb = *reinterpret_cast<const bf16x8*>(
                    &Ks[(nb * 16 + ln16) * KP + kki * 32 + quad * 8]);
                aS[nb] = MFMA16(kb, qf[kki], aS[nb]);
            }

        // ---- p = 2^s; mask only diagonal tile; packed 8B Ps writes ----
        if (kt == j) {
#pragma unroll
            for (int nb = 0; nb < 4; nb++) {
                bf16x4 pv;
#pragma unroll
                for (int r = 0; r < 4; r++) {
                    float p = __builtin_amdgcn_exp2f(aS[nb][r]);
                    if ((nb * 16 + quad * 4 + r) > qloc) p = 0.f;
                    pv[r] = (bf16)p;
                }
                *reinterpret_cast<bf16x4*>(&Ps[qloc * KP + nb * 16 + quad * 4]) = pv;
            }
        } else {
#pragma unroll
            for (int nb = 0; nb < 4; nb++) {
                bf16x4 pv;
#pragma unroll
                for (int r = 0; r < 4; r++)
                    pv[r] = (bf16)__builtin_amdgcn_exp2f(aS[nb][r]);
                *reinterpret_cast<bf16x4*>(&Ps[qloc * KP + nb * 16 + quad * 4]) = pv;
            }
        }
        // wave-private Ps round-trip: wait own DS writes only (no barrier)
        asm volatile("s_waitcnt lgkmcnt(0)" ::: "memory");

        // ---- O^T += V^T P^T ; ones-operand MFMA accumulates l ----
#pragma unroll
        for (int kki = 0; kki < 2; kki++) {
            bf16x8 pa = *reinterpret_cast<const bf16x8*>(
                &Ps[qloc * KP + kki * 32 + quad * 8]);
#pragma unroll
            for (int nb = 0; nb < 4; nb++) {
                bf16x8 vb = *reinterpret_cast<const bf16x8*>(
                    &VTs[(nb * 16 + ln16) * KP + kki * 32 + quad * 8]);
                accO[nb] = MFMA16(vb, pa, accO[nb]);
            }
            accO[4] = MFMA16(vones, pa, accO[4]);
        }
    }

    // ---- epilogue: lane owns q-row = qloc; l = accO[4][0]; packed 8B ----
    const float linv = 1.0f / accO[4][0];
    const size_t zr = ((size_t)b * Tn + q0 + qloc) * Dm + h * 64;
#pragma unroll
    for (int nb = 0; nb < 4; nb++) {
        bf16x4 v;
#pragma unroll
        for (int r = 0; r < 4; r++) v[r] = (bf16)(accO[nb][r] * linv);
        *reinterpret_cast<bf16x4*>(z + zr + nb * 16 + quad * 4) = v;
    }
}

// ---------------------------------------------------------------------------
extern "C" void kernel_launch(void* const* d_in, const int* in_sizes, int n_in,
                              void* d_out, int out_size, void* d_ws, size_t ws_size,
                              hipStream_t stream)
{
    constexpr int B = 2, T = 2048, D = 1024;
    constexpr int M = B * T;  // 4096

    const float* X    = (const float*)d_in[0];
    const float* Wqkv = (const float*)d_in[1];
    const float* Wout = (const float*)d_in[2];
    float* out = (float*)d_out;

    // ws: qk [M][2048] 16 MiB | vt [1024][M] 8 MiB | z [M][1024] 8 MiB
    bf16* qk  = (bf16*)d_ws;
    bf16* vt  = qk + (size_t)M * 2048;
    bf16* zbf = vt + (size_t)1024 * M;
    // d_out as scratch until gemm_out writes it
    bf16* Xbf    = (bf16*)d_out;
    bf16* Wqkvbf = Xbf + (size_t)M * D;
    bf16* Woutbf = qk;  // reuse qk region after attention consumed it

    dim3 blk(256);
    const int n1 = M * D / 8, n2 = 3 * D * D / 8;
    cvt2<<<(n1 + n2 + 255) / 256, blk, 0, stream>>>(X, Wqkv, Xbf, n1, n1 + n2);

    gemm_qkv<<<dim3(24, 32), blk, 0, stream>>>(Xbf, Wqkvbf, qk, vt);

    attn_flash6<<<dim3(1024), blk, 0, stream>>>(qk, vt, zbf);

    const int n3 = D * D / 8;
    cvt2<<<(n3 + 255) / 256, blk, 0, stream>>>(Wout, Wout, Woutbf, n3, n3);

    gemm_out<<<dim3(8, 32), blk, 0, stream>>>(zbf, Woutbf, out);
}